// Round 7
// baseline (348.311 us; speedup 1.0000x reference)
//
#include <hip/hip_runtime.h>
#include <cstdint>
#include <cstddef>

typedef __bf16 bf16;
typedef __bf16 bf16x4 __attribute__((ext_vector_type(4)));
typedef __bf16 bf16x8 __attribute__((ext_vector_type(8)));
typedef float floatx4 __attribute__((ext_vector_type(4)));
typedef float floatx8 __attribute__((ext_vector_type(8)));
typedef unsigned int u32;

constexpr int Bb = 4, Ll = 4096, Dd = 1024;
constexpr int M  = Bb * Ll;          // 16384 rows
constexpr int NC = 64, CT = 64;      // chunks per sequence, chunk length

// async 16B global->LDS (width=16 emits global_load_lds_dwordx4)
typedef const __attribute__((address_space(1))) u32 glb_u32;
typedef __attribute__((address_space(3))) u32 lds_u32;
__device__ __forceinline__ void gld16(const bf16* g, bf16* l) {
  __builtin_amdgcn_global_load_lds((glb_u32*)g, (lds_u32*)l, 16, 0, 0);
}
// raw barrier (no vmcnt drain) + compiler memory fence
__device__ __forceinline__ void bar() {
  __builtin_amdgcn_s_barrier();
  asm volatile("" ::: "memory");
}

// ---------------- W f32 -> bf16 converts ----------------
__global__ __launch_bounds__(256) void convw(
    const float* __restrict__ W, bf16* __restrict__ Wb)
{
  size_t base = ((size_t)blockIdx.x * 256 + threadIdx.x) * 8;
  floatx8 w = *(const floatx8*)(W + base);
  bf16x8 o;
  #pragma unroll
  for (int j = 0; j < 8; ++j) o[j] = (bf16)w[j];
  *(bf16x8*)(Wb + base) = o;
}

__global__ __launch_bounds__(256) void convw3(
    const float* __restrict__ Wa, const float* __restrict__ Wbp, const float* __restrict__ Wc,
    bf16* __restrict__ oa, bf16* __restrict__ ob, bf16* __restrict__ oc)
{
  const float* s = blockIdx.y == 0 ? Wa : (blockIdx.y == 1 ? Wbp : Wc);
  bf16*        d = blockIdx.y == 0 ? oa : (blockIdx.y == 1 ? ob  : oc);
  size_t base = ((size_t)blockIdx.x * 256 + threadIdx.x) * 8;
  floatx8 w = *(const floatx8*)(s + base);
  bf16x8 o;
  #pragma unroll
  for (int j = 0; j < 8; ++j) o[j] = (bf16)w[j];
  *(bf16x8*)(d + base) = o;
}

// ---------------- prep: token-shift mix for all three branches in ONE x pass ----
__global__ __launch_bounds__(256) void prep3(
    const float* __restrict__ x, const float* __restrict__ ma, const float* __restrict__ mb,
    const float* __restrict__ mc,
    bf16* __restrict__ oa, bf16* __restrict__ ob, bf16* __restrict__ oc)
{
  size_t base = ((size_t)blockIdx.x * 256 + threadIdx.x) * 8;
  int d = (int)(base & (size_t)(Dd - 1));
  int l = (int)((base / Dd) & (size_t)(Ll - 1));
  floatx8 xc = *(const floatx8*)(x + base);
  floatx8 xp = l ? *(const floatx8*)(x + base - Dd) : (floatx8)(0.0f);
  floatx8 a = *(const floatx8*)(ma + d);
  floatx8 b = *(const floatx8*)(mb + d);
  floatx8 c = *(const floatx8*)(mc + d);
  bf16x8 ra, rb, rc;
  #pragma unroll
  for (int j = 0; j < 8; ++j) {
    ra[j] = (bf16)(xc[j] * a[j] + xp[j] * (1.0f - a[j]));
    rb[j] = (bf16)(xc[j] * b[j] + xp[j] * (1.0f - b[j]));
    rc[j] = (bf16)(xc[j] * c[j] + xp[j] * (1.0f - c[j]));
  }
  *(bf16x8*)(oa + base) = ra;
  *(bf16x8*)(ob + base) = rb;
  *(bf16x8*)(oc + base) = rc;
}

// ---------------- GEMM: 128x256 tile, BK=32, 8 waves, 2 blocks/CU, 3-slot pipeline ----
// C[m,n] = sum_k A[m,k]*W[n,k]; A,W bf16.
// Occupancy is the lever this round: 512 blocks (2/CU), 72 KiB LDS, VGPR<=128.
// Per K-tile t (32 total), ONE barrier + ONE counted vmcnt:
//   vmcnt(3);   // retires T(t)'s 3 loads/thread, staged TWO iters earlier (~1600cy
//               // cover >> ~900cy HBM latency) -> stall-free by construction;
//               // only T(t+1)'s 3 remain outstanding
//   bar();      // => every thread's T(t) DMAs resident; every wave done reading T(t-1)
//   stage T(t+2) -> slot (t+2)%3  // overwrites T(t-1)'s slot: WAR-safe post-bar
//   8 ds_read_b128 (a[4],b[4]) + 16 MFMA  // compiler-interleaved (fine lgkmcnt)
// Reads of T(t-1) are all consumed by iter t-1's MFMAs (lgkm-drained) before the
// barrier -> no DMA-write/ds_read race (the R5 bug class, re-derived ledger).
// LDS swizzle (BK=32, 4x16B units/row): read unit' = cu ^ ((row>>1)&3); DMA dest
// linear, global SOURCE column pre-swizzled (same involution; R4-verified, 0 conflicts).
// Accumulation order over k unchanged -> bitwise-identical output.
template <int ACT>
__global__ __launch_bounds__(512, 4) void gemmP(
    const bf16* __restrict__ A, const bf16* __restrict__ W, void* __restrict__ Cout)
{
  __shared__ __align__(16) bf16 sm[36864];  // 3 slots x (A 4096 | B 8192) elems = 72 KiB
  const int tid  = threadIdx.x;
  const int lane = tid & 63;
  const int w    = tid >> 6;              // 0..7
  const int wm   = (w >> 2) * 64;         // 2 waves along M (tile 128)
  const int wn   = (w & 3) * 64;          // 4 waves along N (tile 256)
  const int fr   = lane & 15;
  const int cu   = lane >> 4;             // 0..3
  const int soff = ((cu ^ ((fr >> 1) & 3)) << 3);  // swizzled 16B-unit, elems

  // XCD-bijective remap: 512 blocks, 8 XCDs, chunk 64 (512%8==0)
  const int flat = (int)(blockIdx.y * 4 + blockIdx.x);
  const int nid  = (flat & 7) * 64 + (flat >> 3);
  const int m0   = (nid >> 2) * 128, n0 = (nid & 3) * 256;

  // staging: A tile 128x32 = 512 16B-units (1/thread); B tile 256x32 = 1024 (2/thread)
  const int rA  = tid >> 2;
  const int cA  = (((tid & 3) ^ ((rA >> 1) & 3)) << 3);
  const int uB1 = tid + 512;
  const int rB0 = tid >> 2, cB0 = cA;
  const int rB1 = uB1 >> 2, cB1 = (((uB1 & 3) ^ ((rB1 >> 1) & 3)) << 3);
  const bf16* gA  = A + (size_t)(m0 + rA)  * Dd + cA;
  const bf16* gB0 = W + (size_t)(n0 + rB0) * Dd + cB0;
  const bf16* gB1 = W + (size_t)(n0 + rB1) * Dd + cB1;

  auto stage = [&](int slot, int t) {
    const size_t kt = (size_t)(t > 31 ? 31 : t) * 32;   // tail: harmless dup of tile 31
    bf16* s = sm + slot * 12288;
    gld16(gA  + kt, s + (size_t)tid * 8);
    gld16(gB0 + kt, s + 4096 + (size_t)tid * 8);
    gld16(gB1 + kt, s + 4096 + (size_t)uB1 * 8);
  };

  floatx4 acc[4][4];
  #pragma unroll
  for (int i = 0; i < 4; ++i)
    #pragma unroll
    for (int j = 0; j < 4; ++j)
      acc[i][j] = (floatx4)(0.0f);

  // prologue: stage T0, T1 (6 loads outstanding)
  stage(0, 0);
  stage(1, 1);

  bf16x8 a[4], b[4];
  int scur = 0;                              // slot of T(t)
  for (int t = 0; t < 32; ++t) {
    asm volatile("s_waitcnt vmcnt(3)" ::: "memory");   // T(t) resident (mine)
    bar();                                             // everyone's T(t) resident;
                                                       // everyone done reading T(t-1)
    int sstg = scur + 2; if (sstg >= 3) sstg -= 3;
    stage(sstg, t + 2);                                // overwrite T(t-1)'s slot (safe)

    const bf16* sA = sm + scur * 12288;
    const bf16* sB = sA + 4096;
    #pragma unroll
    for (int i = 0; i < 4; ++i)
      a[i] = *(const bf16x8*)(sA + (wm + fr + i * 16) * 32 + soff);
    #pragma unroll
    for (int j = 0; j < 4; ++j)
      b[j] = *(const bf16x8*)(sB + (wn + fr + j * 16) * 32 + soff);

    __builtin_amdgcn_s_setprio(1);
    #pragma unroll
    for (int i = 0; i < 4; ++i)
      #pragma unroll
      for (int j = 0; j < 4; ++j)
        acc[i][j] = __builtin_amdgcn_mfma_f32_16x16x32_bf16(a[i], b[j], acc[i][j], 0, 0, 0);
    __builtin_amdgcn_s_setprio(0);

    scur = (scur + 1 == 3) ? 0 : scur + 1;
  }
  asm volatile("s_waitcnt vmcnt(0)" ::: "memory");

  // epilogue: C/D layout col = lane&15, row = (lane>>4)*4 + reg
  #pragma unroll
  for (int mi = 0; mi < 4; ++mi) {
    int rbase = m0 + wm + mi * 16 + (lane >> 4) * 4;
    #pragma unroll
    for (int j = 0; j < 4; ++j) {
      int col = n0 + wn + j * 16 + (lane & 15);
      #pragma unroll
      for (int r = 0; r < 4; ++r) {
        float v = acc[mi][j][r];
        size_t off = (size_t)(rbase + r) * Dd + col;
        if (ACT == 0)      ((float*)Cout)[off] = v;
        else if (ACT == 1) ((bf16*)Cout)[off]  = (bf16)(1.0f / (1.0f + __expf(-v)));
        else               ((bf16*)Cout)[off]  = (bf16)v;
      }
    }
  }
}

// ---------------- WKV chunked scan — VECTORIZED 4 ch/thread (bf16x4 = 8B/lane) ----
__global__ __launch_bounds__(256) void scan_partial(
    const bf16* __restrict__ k, const bf16* __restrict__ v,
    const float* __restrict__ td, float* __restrict__ Pa, float* __restrict__ Pb)
{
  const int pair = blockIdx.x;            // b*NC + c
  const int b = pair >> 6, c = pair & (NC - 1);
  const int d0 = threadIdx.x * 4;
  floatx4 tdv = *(const floatx4*)(td + d0);
  float decay[4], pa[4], pb[4];
  #pragma unroll
  for (int j = 0; j < 4; ++j) {
    decay[j] = __expf(-__expf(tdv[j]));
    pa[j] = 0.0f; pb[j] = 0.0f;
  }
  size_t base = ((size_t)(b * Ll + c * CT)) * Dd + d0;
  #pragma unroll 4
  for (int t = 0; t < CT; ++t) {
    size_t idx = base + (size_t)t * Dd;
    bf16x4 kk = *(const bf16x4*)(k + idx);
    bf16x4 vv = *(const bf16x4*)(v + idx);
    #pragma unroll
    for (int j = 0; j < 4; ++j) {
      float ek = __expf((float)kk[j]);
      pa[j] = decay[j] * pa[j] + ek * (float)vv[j];
      pb[j] = decay[j] * pb[j] + ek;
    }
  }
  size_t o = (size_t)pair * Dd + d0;
  floatx4 outa, outb;
  #pragma unroll
  for (int j = 0; j < 4; ++j) { outa[j] = pa[j]; outb[j] = pb[j]; }
  *(floatx4*)(Pa + o) = outa;
  *(floatx4*)(Pb + o) = outb;
}

__global__ __launch_bounds__(256) void scan_combine(
    const float* __restrict__ td, const float* __restrict__ Pa, const float* __restrict__ Pb,
    float* __restrict__ A0, float* __restrict__ B0)
{
  int d = blockIdx.x * 256 + threadIdx.x;
  int b = blockIdx.y;
  float dT = __expf(-__expf(td[d]) * (float)CT);   // decay^CT
  float a = 0.0f, bb = 0.0f;
  for (int c = 0; c < NC; ++c) {
    size_t o = ((size_t)(b * NC + c)) * Dd + d;
    A0[o] = a; B0[o] = bb;
    a  = dT * a  + Pa[o];
    bb = dT * bb + Pb[o];
  }
}

// y written IN-PLACE over v (thread-local read-before-write at identical index)
__global__ __launch_bounds__(256) void scan_final(
    const bf16* __restrict__ k, bf16* __restrict__ vy, const bf16* __restrict__ r,
    const float* __restrict__ td, const float* __restrict__ tf,
    const float* __restrict__ A0, const float* __restrict__ B0)
{
  const int pair = blockIdx.x;            // b*NC + c
  const int b = pair >> 6, c = pair & (NC - 1);
  const int d0 = threadIdx.x * 4;
  floatx4 tdv = *(const floatx4*)(td + d0);
  floatx4 tfv = *(const floatx4*)(tf + d0);
  size_t o = (size_t)pair * Dd + d0;
  floatx4 av = *(const floatx4*)(A0 + o);
  floatx4 bv = *(const floatx4*)(B0 + o);
  float decay[4], u[4], a[4], bb[4];
  #pragma unroll
  for (int j = 0; j < 4; ++j) {
    decay[j] = __expf(-__expf(tdv[j]));
    u[j] = tfv[j]; a[j] = av[j]; bb[j] = bv[j];
  }
  size_t base = ((size_t)(b * Ll + c * CT)) * Dd + d0;
  #pragma unroll 2
  for (int t = 0; t < CT; ++t) {
    size_t idx = base + (size_t)t * Dd;
    bf16x4 kk = *(const bf16x4*)(k + idx);
    bf16x4 vv = *(const bf16x4*)(vy + idx);
    bf16x4 rr4 = *(const bf16x4*)(r + idx);
    bf16x4 y;
    #pragma unroll
    for (int j = 0; j < 4; ++j) {
      float kkj = (float)kk[j];
      float vvj = (float)vv[j];
      float eku = __expf(u[j] + kkj);
      float wkv = (a[j] + eku * vvj) / fmaxf(bb[j] + eku, 1e-6f);
      y[j] = (bf16)((float)rr4[j] * wkv);
      float ek = __expf(kkj);
      a[j]  = decay[j] * a[j]  + ek * vvj;
      bb[j] = decay[j] * bb[j] + ek;
    }
    *(bf16x4*)(vy + idx) = y;
  }
}

// ---------------- launch ----------------
extern "C" void kernel_launch(void* const* d_in, const int* in_sizes, int n_in,
                              void* d_out, int out_size, void* d_ws, size_t ws_size,
                              hipStream_t stream)
{
  const float* x  = (const float*)d_in[0];
  const float* td = (const float*)d_in[1];
  const float* tf = (const float*)d_in[2];
  const float* mk = (const float*)d_in[3];
  const float* mv = (const float*)d_in[4];
  const float* mr = (const float*)d_in[5];
  const float* Wk = (const float*)d_in[6];
  const float* Wv = (const float*)d_in[7];
  const float* Wr = (const float*)d_in[8];
  const float* Wo = (const float*)d_in[9];
  float* out = (float*)d_out;           // output f32 (reference dtype)

  // ws: 3 bf16 [M,D] buffers (phased) + 4 partial arrays = exactly 100 MiB
  char* ws = (char*)d_ws;
  const size_t S2 = (size_t)M * Dd * sizeof(bf16);   // 33,554,432 B
  const size_t SP = (size_t)Bb * NC * Dd;            // 262,144 elems
  bf16* buf1 = (bf16*)(ws);              // xmk -> v -> y
  bf16* buf2 = (bf16*)(ws + S2);         // xmv
  bf16* buf3 = (bf16*)(ws + 2 * S2);     // xmr -> k (bf16)
  float* Pa = (float*)(ws + 3 * S2);
  float* Pb = Pa + SP;
  float* A0 = Pb + SP;
  float* B0 = A0 + SP;

  // scratch parked in d_out (dead before the final f32 write):
  //   lower 32 MiB: sigmoid(r) bf16
  //   upper region: Wk/Wv/Wr bf16 (2 MiB each), dead after their gemms
  char* ob  = (char*)d_out;
  bf16* rr  = (bf16*)d_out;
  bf16* Wkb = (bf16*)(ob + ((size_t)32 << 20));
  bf16* Wvb = (bf16*)(ob + ((size_t)34 << 20));
  bf16* Wrb = (bf16*)(ob + ((size_t)36 << 20));
  // Wo bf16 (2 MiB) overlays Pa+Pb, which die after scan_combine
  bf16* Wob = (bf16*)Pa;

  dim3 gp((unsigned)((size_t)M * Dd / (256 * 8)));   // 8192 blocks
  dim3 gw((unsigned)((size_t)Dd * Dd / (256 * 8)));  // 512 blocks
  dim3 gg(Dd / 256, M / 128);                        // (4, 128) = 512 blocks = 2/CU

  convw3<<<dim3(gw.x, 3), 256, 0, stream>>>(Wk, Wv, Wr, Wkb, Wvb, Wrb);

  // ONE x pass for all three token-shift mixes
  prep3<<<gp, 256, 0, stream>>>(x, mk, mv, mr, buf1, buf2, buf3);  // xmk, xmv, xmr

  gemmP<1><<<gg, 512, 0, stream>>>(buf3, Wrb, rr);               // sigmoid(r) -> d_out lo; buf3 dead
  gemmP<2><<<gg, 512, 0, stream>>>(buf1, Wkb, buf3);             // k  (bf16)  buf1 dead
  gemmP<2><<<gg, 512, 0, stream>>>(buf2, Wvb, buf1);             // v  (bf16)  buf2 dead

  scan_partial<<<dim3(Bb * NC), 256, 0, stream>>>(buf3, buf1, td, Pa, Pb);
  scan_combine<<<dim3(Dd / 256, Bb), 256, 0, stream>>>(td, Pa, Pb, A0, B0);
  convw<<<gw, 256, 0, stream>>>(Wo, Wob);                        // Pa/Pb now dead
  scan_final  <<<dim3(Bb * NC), 256, 0, stream>>>(buf3, buf1, rr, td, tf, A0, B0);

  gemmP<0><<<gg, 512, 0, stream>>>(buf1, Wob, out);              // y·Wo -> d_out (f32)
}

// Round 8
// 348.285 us; speedup vs baseline: 1.0001x; 1.0001x over previous
//
#include <hip/hip_runtime.h>
#include <cstdint>
#include <cstddef>

typedef __bf16 bf16;
typedef __bf16 bf16x4 __attribute__((ext_vector_type(4)));
typedef __bf16 bf16x8 __attribute__((ext_vector_type(8)));
typedef float floatx4 __attribute__((ext_vector_type(4)));
typedef float floatx8 __attribute__((ext_vector_type(8)));
typedef unsigned int u32;

constexpr int Bb = 4, Ll = 4096, Dd = 1024;
constexpr int M  = Bb * Ll;          // 16384 rows
constexpr int NC = 64, CT = 64;      // chunks per sequence, chunk length

// async 16B global->LDS (width=16 emits global_load_lds_dwordx4)
typedef const __attribute__((address_space(1))) u32 glb_u32;
typedef __attribute__((address_space(3))) u32 lds_u32;
__device__ __forceinline__ void gld16(const bf16* g, bf16* l) {
  __builtin_amdgcn_global_load_lds((glb_u32*)g, (lds_u32*)l, 16, 0, 0);
}
// raw barrier (no vmcnt drain) + compiler memory fence
__device__ __forceinline__ void bar() {
  __builtin_amdgcn_s_barrier();
  asm volatile("" ::: "memory");
}

// ---------------- W f32 -> bf16 converts ----------------
__global__ __launch_bounds__(256) void convw(
    const float* __restrict__ W, bf16* __restrict__ Wb)
{
  size_t base = ((size_t)blockIdx.x * 256 + threadIdx.x) * 8;
  floatx8 w = *(const floatx8*)(W + base);
  bf16x8 o;
  #pragma unroll
  for (int j = 0; j < 8; ++j) o[j] = (bf16)w[j];
  *(bf16x8*)(Wb + base) = o;
}

__global__ __launch_bounds__(256) void convw3(
    const float* __restrict__ Wa, const float* __restrict__ Wbp, const float* __restrict__ Wc,
    bf16* __restrict__ oa, bf16* __restrict__ ob, bf16* __restrict__ oc)
{
  const float* s = blockIdx.y == 0 ? Wa : (blockIdx.y == 1 ? Wbp : Wc);
  bf16*        d = blockIdx.y == 0 ? oa : (blockIdx.y == 1 ? ob  : oc);
  size_t base = ((size_t)blockIdx.x * 256 + threadIdx.x) * 8;
  floatx8 w = *(const floatx8*)(s + base);
  bf16x8 o;
  #pragma unroll
  for (int j = 0; j < 8; ++j) o[j] = (bf16)w[j];
  *(bf16x8*)(d + base) = o;
}

// ---------------- prep: token-shift mix for all three branches in ONE x pass ----
__global__ __launch_bounds__(256) void prep3(
    const float* __restrict__ x, const float* __restrict__ ma, const float* __restrict__ mb,
    const float* __restrict__ mc,
    bf16* __restrict__ oa, bf16* __restrict__ ob, bf16* __restrict__ oc)
{
  size_t base = ((size_t)blockIdx.x * 256 + threadIdx.x) * 8;
  int d = (int)(base & (size_t)(Dd - 1));
  int l = (int)((base / Dd) & (size_t)(Ll - 1));
  floatx8 xc = *(const floatx8*)(x + base);
  floatx8 xp = l ? *(const floatx8*)(x + base - Dd) : (floatx8)(0.0f);
  floatx8 a = *(const floatx8*)(ma + d);
  floatx8 b = *(const floatx8*)(mb + d);
  floatx8 c = *(const floatx8*)(mc + d);
  bf16x8 ra, rb, rc;
  #pragma unroll
  for (int j = 0; j < 8; ++j) {
    ra[j] = (bf16)(xc[j] * a[j] + xp[j] * (1.0f - a[j]));
    rb[j] = (bf16)(xc[j] * b[j] + xp[j] * (1.0f - b[j]));
    rc[j] = (bf16)(xc[j] * c[j] + xp[j] * (1.0f - c[j]));
  }
  *(bf16x8*)(oa + base) = ra;
  *(bf16x8*)(ob + base) = rb;
  *(bf16x8*)(oc + base) = rc;
}

// ---------------- GEMM: 256x256 tile, BK=32, 8 waves, DEPTH-3 pipeline ----------------
// C[m,n] = sum_k A[m,k]*W[n,k]; A,W bf16.  Wave-tile 128x64 (min LDS traffic/FLOP).
// Theory (R7 post-mortem): all prior schedules stalled because prefetch depth
// (2-3 phases ~<2.5k cyc) < loaded A-load latency (~2.5-3.3k cyc: L3/HBM stream +
// queueing).  Fix: 4 LDS slots of 32 KiB (BK=32), stage K-tile t+3 during iter t
// -> issue-to-wait distance 5-6 phases (~4-5k cyc) > latency => stall-free wait.
// Per iter (K-tile, 2 phases, m201 phase shape {reads; stage; bar; MFMA; bar}):
//   top:  vmcnt(8)  // per-thread FIFO: outstanding = T(t+1)4,T(t+2)4,(T(t+3) not
//                   // yet) + ... = 12 -> retires exactly T(t) (issued iter t-3)
//         bar       // everyone's T(t) resident; everyone done reading T(t-1)
//   P0: ds_read a03(4)+b(4); stage T(t+3).A (2 gld16, slot (t+3)&3 = T(t-1) slot,
//       WAR-safe post-bar); bar; 16 MFMA acc[0..3][*]; bar
//   P1: ds_read a47(4);      stage T(t+3).B; bar; 16 MFMA acc[4..7][*]
// k-order per acc element: ascending 32-steps, one MFMA per K-tile -> bitwise
// identical accumulation to R6 (passing).
// XCD remap: mp=(flat&7)+8*(q>>2), nb=q&3 (q=flat>>3) -> the 4 n-blocks sharing an
// A-panel land on ONE XCD (flat&7) -> A L2-shared, lower effective load latency.
// LDS swizzle (BK=32): read unit' = cu ^ ((fr>>1)&3); DMA dest linear, global
// source column pre-swizzled with the same involution (R7-verified, 0 conflicts).
template <int ACT>
__global__ __launch_bounds__(512, 2) void gemmQ(
    const bf16* __restrict__ A, const bf16* __restrict__ W, void* __restrict__ Cout)
{
  __shared__ __align__(16) bf16 sm[65536];  // 4 slots x (A 8192 | B 8192) = 128 KiB
  const int tid  = threadIdx.x;
  const int lane = tid & 63;
  const int w    = tid >> 6;              // 0..7
  const int wm   = (w >> 2) * 128;        // 2 waves along M
  const int wn   = (w & 3) * 64;          // 4 waves along N
  const int fr   = lane & 15;
  const int cu   = lane >> 4;             // 0..3
  const int soff = ((cu ^ ((fr >> 1) & 3)) << 3);  // swizzled 16B-unit, elems

  // XCD remap: 256 blocks; 4 n-blocks of one m-panel -> same XCD
  const int flat = (int)(blockIdx.y * 4 + blockIdx.x);
  const int q    = flat >> 3, r8 = flat & 7;
  const int mp   = r8 + 8 * (q >> 2);     // 0..63
  const int nb   = q & 3;                 // 0..3
  const int m0   = mp * 256, n0 = nb * 256;

  // staging: per operand tile 256 rows x 32 cols = 1024 16B-units; thread covers u, u+512
  const int u0 = tid, u1 = tid + 512;
  const int r0 = u0 >> 2, c0 = (((u0 & 3) ^ ((r0 >> 1) & 3)) << 3);
  const int r1 = u1 >> 2, c1 = (((u1 & 3) ^ ((r1 >> 1) & 3)) << 3);
  const bf16* gA0 = A + (size_t)(m0 + r0) * Dd + c0;
  const bf16* gA1 = A + (size_t)(m0 + r1) * Dd + c1;
  const bf16* gB0 = W + (size_t)(n0 + r0) * Dd + c0;
  const bf16* gB1 = W + (size_t)(n0 + r1) * Dd + c1;

  auto stageA = [&](int slot, int t) {
    const size_t kt = (size_t)(t > 31 ? 31 : t) * 32;  // tail: dup of tile 31 (never read)
    bf16* s = sm + slot * 16384;
    gld16(gA0 + kt, s + (size_t)u0 * 8);
    gld16(gA1 + kt, s + (size_t)u1 * 8);
  };
  auto stageB = [&](int slot, int t) {
    const size_t kt = (size_t)(t > 31 ? 31 : t) * 32;
    bf16* s = sm + slot * 16384 + 8192;
    gld16(gB0 + kt, s + (size_t)u0 * 8);
    gld16(gB1 + kt, s + (size_t)u1 * 8);
  };

  floatx4 acc[8][4];
  #pragma unroll
  for (int i = 0; i < 8; ++i)
    #pragma unroll
    for (int j = 0; j < 4; ++j)
      acc[i][j] = (floatx4)(0.0f);

  // prologue: stage T0,T1,T2 (12 loads outstanding)
  stageA(0, 0); stageB(0, 0);
  stageA(1, 1); stageB(1, 1);
  stageA(2, 2); stageB(2, 2);

  bf16x8 a03[4], a47[4], b[4];
  for (int t = 0; t < 32; ++t) {
    const int scur = t & 3;
    const int sstg = (t + 3) & 3;
    asm volatile("s_waitcnt vmcnt(8)" ::: "memory");   // retire T(t) (issued iter t-3)
    bar();                                             // T(t) resident block-wide;
                                                       // T(t-1) reads all done
    const bf16* sA = sm + scur * 16384;
    const bf16* sB = sA + 8192;

    // ---- P0: reads a03 + b; stage T(t+3).A ----
    #pragma unroll
    for (int i = 0; i < 4; ++i)
      a03[i] = *(const bf16x8*)(sA + (wm + fr + i * 16) * 32 + soff);
    #pragma unroll
    for (int j = 0; j < 4; ++j)
      b[j] = *(const bf16x8*)(sB + (wn + fr + j * 16) * 32 + soff);
    stageA(sstg, t + 3);
    bar();
    __builtin_amdgcn_s_setprio(1);
    #pragma unroll
    for (int i = 0; i < 4; ++i)
      #pragma unroll
      for (int j = 0; j < 4; ++j)
        acc[i][j] = __builtin_amdgcn_mfma_f32_16x16x32_bf16(a03[i], b[j], acc[i][j], 0, 0, 0);
    __builtin_amdgcn_s_setprio(0);
    bar();

    // ---- P1: reads a47; stage T(t+3).B ----
    #pragma unroll
    for (int i = 0; i < 4; ++i)
      a47[i] = *(const bf16x8*)(sA + (wm + 64 + fr + i * 16) * 32 + soff);
    stageB(sstg, t + 3);
    bar();
    __builtin_amdgcn_s_setprio(1);
    #pragma unroll
    for (int i = 0; i < 4; ++i)
      #pragma unroll
      for (int j = 0; j < 4; ++j)
        acc[i + 4][j] = __builtin_amdgcn_mfma_f32_16x16x32_bf16(a47[i], b[j], acc[i + 4][j], 0, 0, 0);
    __builtin_amdgcn_s_setprio(0);
    // loop-closing bar is next iter's opening bar
  }
  asm volatile("s_waitcnt vmcnt(0)" ::: "memory");

  // epilogue: C/D layout col = lane&15, row = (lane>>4)*4 + reg
  #pragma unroll
  for (int mi = 0; mi < 8; ++mi) {
    int rbase = m0 + wm + mi * 16 + (lane >> 4) * 4;
    #pragma unroll
    for (int j = 0; j < 4; ++j) {
      int col = n0 + wn + j * 16 + (lane & 15);
      #pragma unroll
      for (int r = 0; r < 4; ++r) {
        float v = acc[mi][j][r];
        size_t off = (size_t)(rbase + r) * Dd + col;
        if (ACT == 0)      ((float*)Cout)[off] = v;
        else if (ACT == 1) ((bf16*)Cout)[off]  = (bf16)(1.0f / (1.0f + __expf(-v)));
        else               ((bf16*)Cout)[off]  = (bf16)v;
      }
    }
  }
}

// ---------------- WKV chunked scan — VECTORIZED 4 ch/thread (bf16x4 = 8B/lane) ----
__global__ __launch_bounds__(256) void scan_partial(
    const bf16* __restrict__ k, const bf16* __restrict__ v,
    const float* __restrict__ td, float* __restrict__ Pa, float* __restrict__ Pb)
{
  const int pair = blockIdx.x;            // b*NC + c
  const int b = pair >> 6, c = pair & (NC - 1);
  const int d0 = threadIdx.x * 4;
  floatx4 tdv = *(const floatx4*)(td + d0);
  float decay[4], pa[4], pb[4];
  #pragma unroll
  for (int j = 0; j < 4; ++j) {
    decay[j] = __expf(-__expf(tdv[j]));
    pa[j] = 0.0f; pb[j] = 0.0f;
  }
  size_t base = ((size_t)(b * Ll + c * CT)) * Dd + d0;
  #pragma unroll 4
  for (int t = 0; t < CT; ++t) {
    size_t idx = base + (size_t)t * Dd;
    bf16x4 kk = *(const bf16x4*)(k + idx);
    bf16x4 vv = *(const bf16x4*)(v + idx);
    #pragma unroll
    for (int j = 0; j < 4; ++j) {
      float ek = __expf((float)kk[j]);
      pa[j] = decay[j] * pa[j] + ek * (float)vv[j];
      pb[j] = decay[j] * pb[j] + ek;
    }
  }
  size_t o = (size_t)pair * Dd + d0;
  floatx4 outa, outb;
  #pragma unroll
  for (int j = 0; j < 4; ++j) { outa[j] = pa[j]; outb[j] = pb[j]; }
  *(floatx4*)(Pa + o) = outa;
  *(floatx4*)(Pb + o) = outb;
}

__global__ __launch_bounds__(256) void scan_combine(
    const float* __restrict__ td, const float* __restrict__ Pa, const float* __restrict__ Pb,
    float* __restrict__ A0, float* __restrict__ B0)
{
  int d = blockIdx.x * 256 + threadIdx.x;
  int b = blockIdx.y;
  float dT = __expf(-__expf(td[d]) * (float)CT);   // decay^CT
  float a = 0.0f, bb = 0.0f;
  for (int c = 0; c < NC; ++c) {
    size_t o = ((size_t)(b * NC + c)) * Dd + d;
    A0[o] = a; B0[o] = bb;
    a  = dT * a  + Pa[o];
    bb = dT * bb + Pb[o];
  }
}

// y written IN-PLACE over v (thread-local read-before-write at identical index)
__global__ __launch_bounds__(256) void scan_final(
    const bf16* __restrict__ k, bf16* __restrict__ vy, const bf16* __restrict__ r,
    const float* __restrict__ td, const float* __restrict__ tf,
    const float* __restrict__ A0, const float* __restrict__ B0)
{
  const int pair = blockIdx.x;            // b*NC + c
  const int b = pair >> 6, c = pair & (NC - 1);
  const int d0 = threadIdx.x * 4;
  floatx4 tdv = *(const floatx4*)(td + d0);
  floatx4 tfv = *(const floatx4*)(tf + d0);
  size_t o = (size_t)pair * Dd + d0;
  floatx4 av = *(const floatx4*)(A0 + o);
  floatx4 bv = *(const floatx4*)(B0 + o);
  float decay[4], u[4], a[4], bb[4];
  #pragma unroll
  for (int j = 0; j < 4; ++j) {
    decay[j] = __expf(-__expf(tdv[j]));
    u[j] = tfv[j]; a[j] = av[j]; bb[j] = bv[j];
  }
  size_t base = ((size_t)(b * Ll + c * CT)) * Dd + d0;
  #pragma unroll 2
  for (int t = 0; t < CT; ++t) {
    size_t idx = base + (size_t)t * Dd;
    bf16x4 kk = *(const bf16x4*)(k + idx);
    bf16x4 vv = *(const bf16x4*)(vy + idx);
    bf16x4 rr4 = *(const bf16x4*)(r + idx);
    bf16x4 y;
    #pragma unroll
    for (int j = 0; j < 4; ++j) {
      float kkj = (float)kk[j];
      float vvj = (float)vv[j];
      float eku = __expf(u[j] + kkj);
      float wkv = (a[j] + eku * vvj) / fmaxf(bb[j] + eku, 1e-6f);
      y[j] = (bf16)((float)rr4[j] * wkv);
      float ek = __expf(kkj);
      a[j]  = decay[j] * a[j]  + ek * vvj;
      bb[j] = decay[j] * bb[j] + ek;
    }
    *(bf16x4*)(vy + idx) = y;
  }
}

// ---------------- launch ----------------
extern "C" void kernel_launch(void* const* d_in, const int* in_sizes, int n_in,
                              void* d_out, int out_size, void* d_ws, size_t ws_size,
                              hipStream_t stream)
{
  const float* x  = (const float*)d_in[0];
  const float* td = (const float*)d_in[1];
  const float* tf = (const float*)d_in[2];
  const float* mk = (const float*)d_in[3];
  const float* mv = (const float*)d_in[4];
  const float* mr = (const float*)d_in[5];
  const float* Wk = (const float*)d_in[6];
  const float* Wv = (const float*)d_in[7];
  const float* Wr = (const float*)d_in[8];
  const float* Wo = (const float*)d_in[9];
  float* out = (float*)d_out;           // output f32 (reference dtype)

  // ws: 3 bf16 [M,D] buffers (phased) + 4 partial arrays = exactly 100 MiB
  char* ws = (char*)d_ws;
  const size_t S2 = (size_t)M * Dd * sizeof(bf16);   // 33,554,432 B
  const size_t SP = (size_t)Bb * NC * Dd;            // 262,144 elems
  bf16* buf1 = (bf16*)(ws);              // xmk -> v -> y
  bf16* buf2 = (bf16*)(ws + S2);         // xmv
  bf16* buf3 = (bf16*)(ws + 2 * S2);     // xmr -> k (bf16)
  float* Pa = (float*)(ws + 3 * S2);
  float* Pb = Pa + SP;
  float* A0 = Pb + SP;
  float* B0 = A0 + SP;

  // scratch parked in d_out (dead before the final f32 write):
  //   lower 32 MiB: sigmoid(r) bf16
  //   upper region: Wk/Wv/Wr bf16 (2 MiB each), dead after their gemms
  char* ob  = (char*)d_out;
  bf16* rr  = (bf16*)d_out;
  bf16* Wkb = (bf16*)(ob + ((size_t)32 << 20));
  bf16* Wvb = (bf16*)(ob + ((size_t)34 << 20));
  bf16* Wrb = (bf16*)(ob + ((size_t)36 << 20));
  // Wo bf16 (2 MiB) overlays Pa+Pb, which die after scan_combine
  bf16* Wob = (bf16*)Pa;

  dim3 gp((unsigned)((size_t)M * Dd / (256 * 8)));   // 8192 blocks
  dim3 gw((unsigned)((size_t)Dd * Dd / (256 * 8)));  // 512 blocks
  dim3 gg(Dd / 256, M / 256);                        // (4, 64) = 256 blocks

  convw3<<<dim3(gw.x, 3), 256, 0, stream>>>(Wk, Wv, Wr, Wkb, Wvb, Wrb);

  // ONE x pass for all three token-shift mixes
  prep3<<<gp, 256, 0, stream>>>(x, mk, mv, mr, buf1, buf2, buf3);  // xmk, xmv, xmr

  gemmQ<1><<<gg, 512, 0, stream>>>(buf3, Wrb, rr);               // sigmoid(r) -> d_out lo; buf3 dead
  gemmQ<2><<<gg, 512, 0, stream>>>(buf1, Wkb, buf3);             // k  (bf16)  buf1 dead
  gemmQ<2><<<gg, 512, 0, stream>>>(buf2, Wvb, buf1);             // v  (bf16)  buf2 dead

  scan_partial<<<dim3(Bb * NC), 256, 0, stream>>>(buf3, buf1, td, Pa, Pb);
  scan_combine<<<dim3(Dd / 256, Bb), 256, 0, stream>>>(td, Pa, Pb, A0, B0);
  convw<<<gw, 256, 0, stream>>>(Wo, Wob);                        // Pa/Pb now dead
  scan_final  <<<dim3(Bb * NC), 256, 0, stream>>>(buf3, buf1, rr, td, tf, A0, B0);

  gemmQ<0><<<gg, 512, 0, stream>>>(buf1, Wob, out);              // y·Wo -> d_out (f32)
}